// Round 4
// baseline (1628.496 us; speedup 1.0000x reference)
//
#include <hip/hip_runtime.h>

// Problem constants
#define TT   512
#define BB   32
#define DD   1024
#define HH   16
#define NROW 16384   // TT*BB

typedef __attribute__((ext_vector_type(4))) float f32x4;
typedef __attribute__((ext_vector_type(8))) short s16x8;
typedef __attribute__((ext_vector_type(4))) short s16x4;

__device__ __forceinline__ unsigned short f2bf(float f) {
    unsigned int u = __float_as_uint(f);
    u += 0x7fffu + ((u >> 16) & 1u);   // RNE
    return (unsigned short)(u >> 16);
}
__device__ __forceinline__ float bf2f(unsigned short h) {
    return __uint_as_float(((unsigned int)h) << 16);
}

// async global->LDS, 16B per lane; LDS dest is wave-uniform base + lane*16
__device__ __forceinline__ void gload16(const unsigned short* g, unsigned short* l) {
    __builtin_amdgcn_global_load_lds(
        (const __attribute__((address_space(1))) unsigned int*)g,
        (__attribute__((address_space(3))) unsigned int*)l, 16, 0, 0);
}

// ---------------------------------------------------------------------------
// Diagnostic marker fill (only used when ws_size is insufficient)
// ---------------------------------------------------------------------------
__global__ __launch_bounds__(256, 8)
void fill_f32(float* __restrict__ p, float v) {
    const size_t i = ((size_t)blockIdx.x * 256 + threadIdx.x) * 4;
    f32x4 o = (f32x4){v, v, v, v};
    *(f32x4*)(p + i) = o;
}

// ---------------------------------------------------------------------------
// Batched fp32 -> bf16 convert of all 6 weight matrices in one launch.
// ---------------------------------------------------------------------------
__global__ __launch_bounds__(256, 8)
void cvt_weights(const float* __restrict__ s0, const float* __restrict__ s1,
                 const float* __restrict__ s2, const float* __restrict__ s3,
                 const float* __restrict__ s4, const float* __restrict__ s5,
                 unsigned short* __restrict__ dst) {
    const int i = blockIdx.x * 256 + threadIdx.x;   // < 6291456
    const float* src;
    int base;
    if      (i <  786432) { src = s0; base = 0;       }
    else if (i < 1048576) { src = s1; base = 786432;  }
    else if (i < 2097152) { src = s2; base = 1048576; }
    else if (i < 3145728) { src = s3; base = 2097152; }
    else if (i < 4718592) { src = s4; base = 3145728; }
    else                  { src = s5; base = 4718592; }
    f32x4 v = *(const f32x4*)(src + (size_t)(i - base) * 4);
    s16x4 o;
#pragma unroll
    for (int j = 0; j < 4; ++j) o[j] = (short)f2bf(v[j]);
    *(s16x4*)(dst + (size_t)i * 4) = o;
}

// ---------------------------------------------------------------------------
// Row-block fp32 -> bf16 with output leading dim (for x chunk -> xc half 1)
// One block per row; 256 threads x 4 elems = 1024 cols.
// ---------------------------------------------------------------------------
__global__ __launch_bounds__(256, 8)
void cvt_rows(const float* __restrict__ in, unsigned short* __restrict__ out, int ld_out) {
    const int row = blockIdx.x;
    const int d   = threadIdx.x * 4;
    f32x4 v = *(const f32x4*)(in + (size_t)row * DD + d);
    s16x4 o;
#pragma unroll
    for (int j = 0; j < 4; ++j) o[j] = (short)f2bf(v[j]);
    *(s16x4*)(out + (size_t)row * ld_out + d) = o;
}

// ---------------------------------------------------------------------------
// LayerNorm over D=1024, one block per row. Optional side output = bf16(in).
// ---------------------------------------------------------------------------
__global__ __launch_bounds__(256, 4)
void ln_fwd(const float* __restrict__ in, const float* __restrict__ w,
            const float* __restrict__ bsh, unsigned short* __restrict__ out,
            unsigned short* __restrict__ side, int ld_side) {
    const int row = blockIdx.x;
    const int tid = threadIdx.x;
    f32x4 v = *(const f32x4*)(in + (size_t)row * DD + tid * 4);
    float s = v[0] + v[1] + v[2] + v[3];
    float q = v[0]*v[0] + v[1]*v[1] + v[2]*v[2] + v[3]*v[3];
#pragma unroll
    for (int d = 1; d < 64; d <<= 1) {
        s += __shfl_xor(s, d, 64);
        q += __shfl_xor(q, d, 64);
    }
    __shared__ float red[8];
    const int lane = tid & 63, wv = tid >> 6;
    if (lane == 0) { red[wv] = s; red[4 + wv] = q; }
    __syncthreads();
    s = red[0] + red[1] + red[2] + red[3];
    q = red[4] + red[5] + red[6] + red[7];
    const float mu   = s * (1.f / 1024.f);
    const float rstd = rsqrtf(q * (1.f / 1024.f) - mu * mu + 1e-5f);
    f32x4 w4 = *(const f32x4*)(w + tid * 4);
    f32x4 b4 = *(const f32x4*)(bsh + tid * 4);
    s16x4 o;
#pragma unroll
    for (int j = 0; j < 4; ++j) o[j] = (short)f2bf((v[j] - mu) * rstd * w4[j] + b4[j]);
    *(s16x4*)(out + (size_t)row * DD + tid * 4) = o;
    if (side) {
        s16x4 sx;
#pragma unroll
        for (int j = 0; j < 4; ++j) sx[j] = (short)f2bf(v[j]);
        *(s16x4*)(side + (size_t)row * ld_side + tid * 4) = sx;
    }
}

// ---------------------------------------------------------------------------
// GEMM: C[M][ldc] = bf16( act(A[M][K] * W[N][K]^T + bias) )
// 128x128 tile, BK=64, 4 waves, 16x16x32 bf16 MFMA, global_load_lds staging
// with XOR chunk swizzle (chunk c stored at c^(row&7)), swizzled ds_read_b128.
// ---------------------------------------------------------------------------
__global__ __launch_bounds__(256, 2)
void gemm_bf16(const unsigned short* __restrict__ A,
               const unsigned short* __restrict__ W,
               unsigned short* __restrict__ C,
               const float* __restrict__ bias,
               int M, int N, int K, int ldc, int relu) {
    __shared__ unsigned short lds_a[128 * 64];
    __shared__ unsigned short lds_b[128 * 64];

    const int tid  = threadIdx.x;
    const int lane = tid & 63;
    const int wv   = tid >> 6;
    const int wm   = wv >> 1;
    const int wn   = wv & 1;
    const int m0   = blockIdx.y * 128;
    const int n0   = blockIdx.x * 128;
    const int l15  = lane & 15;
    const int l4   = lane >> 4;
    const int lrow   = lane >> 3;          // row within 8-row staging chunk
    const int gchunk = (lane & 7) ^ lrow;  // pre-swizzled source chunk

    f32x4 acc[4][4];
#pragma unroll
    for (int i = 0; i < 4; ++i)
#pragma unroll
        for (int j = 0; j < 4; ++j) acc[i][j] = (f32x4){0.f, 0.f, 0.f, 0.f};

    for (int k0 = 0; k0 < K; k0 += 64) {
        __syncthreads();
#pragma unroll
        for (int i = 0; i < 4; ++i) {
            const int r = (wv * 4 + i) * 8 + lrow;
            gload16(A + (size_t)(m0 + r) * K + k0 + gchunk * 8, lds_a + (wv * 4 + i) * 512);
            gload16(W + (size_t)(n0 + r) * K + k0 + gchunk * 8, lds_b + (wv * 4 + i) * 512);
        }
        __syncthreads();
#pragma unroll
        for (int ks = 0; ks < 2; ++ks) {
            s16x8 af[4], bfr[4];
#pragma unroll
            for (int mi = 0; mi < 4; ++mi) {
                const int row = wm * 64 + mi * 16 + l15;
                const int c   = ks * 4 + l4;
                af[mi] = *(const s16x8*)(lds_a + row * 64 + ((c ^ (row & 7)) * 8));
            }
#pragma unroll
            for (int ni = 0; ni < 4; ++ni) {
                const int row = wn * 64 + ni * 16 + l15;
                const int c   = ks * 4 + l4;
                bfr[ni] = *(const s16x8*)(lds_b + row * 64 + ((c ^ (row & 7)) * 8));
            }
#pragma unroll
            for (int mi = 0; mi < 4; ++mi)
#pragma unroll
                for (int ni = 0; ni < 4; ++ni)
                    acc[mi][ni] = __builtin_amdgcn_mfma_f32_16x16x32_bf16(
                        af[mi], bfr[ni], acc[mi][ni], 0, 0, 0);
        }
    }

    const int r0 = l4 * 4;
#pragma unroll
    for (int ni = 0; ni < 4; ++ni) {
        const int col = n0 + wn * 64 + ni * 16 + l15;
        const float bv = bias ? bias[col] : 0.f;
#pragma unroll
        for (int mi = 0; mi < 4; ++mi) {
            const int rowb = m0 + wm * 64 + mi * 16 + r0;
#pragma unroll
            for (int r = 0; r < 4; ++r) {
                float v = acc[mi][ni][r] + bv;
                if (relu) v = fmaxf(v, 0.f);
                C[(size_t)(rowb + r) * ldc + col] = f2bf(v);
            }
        }
    }
}

// ---------------------------------------------------------------------------
// Repack qkv (row = t*B+b, col = three*1024 + h*64 + dk) into
//   Q,K: [bh][t][dk]  and  Vt: [bh][dk][t]  (transposed via LDS tile)
// ---------------------------------------------------------------------------
__global__ __launch_bounds__(256, 2)
void repack_qkv(const unsigned short* __restrict__ qkv,
                unsigned short* __restrict__ Qo, unsigned short* __restrict__ Ko,
                unsigned short* __restrict__ Vt) {
    __shared__ unsigned short vlds[64][65];
    const int tid = threadIdx.x;
    const int t0  = blockIdx.x * 64;
    const int bh  = blockIdx.y;
    const int b   = bh >> 4, h = bh & 15;
    {
        const int row = tid >> 2, ch = tid & 3;
        const int t = t0 + row;
        const unsigned short* src = qkv + (size_t)(t * BB + b) * 3072 + h * 64 + ch * 16;
        const size_t doff = ((size_t)bh * 512 + t) * 64 + ch * 16;
        *(s16x8*)(Qo + doff)     = *(const s16x8*)(src);
        *(s16x8*)(Qo + doff + 8) = *(const s16x8*)(src + 8);
        *(s16x8*)(Ko + doff)     = *(const s16x8*)(src + 1024);
        *(s16x8*)(Ko + doff + 8) = *(const s16x8*)(src + 1032);
    }
#pragma unroll
    for (int it = 0; it < 2; ++it) {
        const int vr = (tid >> 3) + it * 32;
        const int c8 = tid & 7;
        s16x8 val = *(const s16x8*)(qkv + (size_t)((t0 + vr) * BB + b) * 3072 + 2048 + h * 64 + c8 * 8);
#pragma unroll
        for (int j = 0; j < 8; ++j) vlds[vr][c8 * 8 + j] = (unsigned short)val[j];
    }
    __syncthreads();
    {
        const int dk = tid >> 2, ch = tid & 3;
        s16x8 o0, o1;
#pragma unroll
        for (int j = 0; j < 8; ++j) {
            o0[j] = (short)vlds[ch * 16 + j][dk];
            o1[j] = (short)vlds[ch * 16 + 8 + j][dk];
        }
        const size_t doff = ((size_t)bh * 64 + dk) * 512 + t0 + ch * 16;
        *(s16x8*)(Vt + doff)     = o0;
        *(s16x8*)(Vt + doff + 8) = o1;
    }
}

// ---------------------------------------------------------------------------
// Causal flash attention. Block = (q-tile of 64, bh). 4 waves x 16 q-rows.
// Q,K: [bh][t][64] bf16; Vt: [bh][64][t] bf16. Out: (t,b, h*64+dk) bf16.
// ---------------------------------------------------------------------------
__global__ __launch_bounds__(256, 2)
void attn_fwd(const unsigned short* __restrict__ Qm,
              const unsigned short* __restrict__ Km,
              const unsigned short* __restrict__ Vt,
              unsigned short* __restrict__ Om) {
    __shared__ unsigned short lds_k[64 * 64];
    __shared__ unsigned short lds_v[64 * 64];
    __shared__ unsigned short p_lds[4][16 * 72];   // stride 72: conflict-free b128 reads

    const int tid  = threadIdx.x;
    const int lane = tid & 63;
    const int wv   = tid >> 6;
    const int q0   = blockIdx.x * 64;
    const int bh   = blockIdx.y;
    const int b    = bh >> 4, h = bh & 15;
    const int l15  = lane & 15;
    const int l4   = lane >> 4;
    const int lrow   = lane >> 3;
    const int gchunk = (lane & 7) ^ lrow;

    // Q fragments (wave's 16 rows), A-layout: row=l15, k=l4*8+j
    s16x8 qa[2];
    {
        const unsigned short* qp = Qm + ((size_t)bh * 512 + q0 + wv * 16 + l15) * 64 + l4 * 8;
        qa[0] = *(const s16x8*)(qp);
        qa[1] = *(const s16x8*)(qp + 32);
    }

    f32x4 oacc[4];
#pragma unroll
    for (int i = 0; i < 4; ++i) oacc[i] = (f32x4){0.f, 0.f, 0.f, 0.f};
    float m_run[4], l_run[4];
#pragma unroll
    for (int r = 0; r < 4; ++r) { m_run[r] = -1e30f; l_run[r] = 0.f; }

    const int rowg0 = q0 + wv * 16 + l4 * 4;

    for (int s0 = 0; s0 <= q0; s0 += 64) {
        __syncthreads();
#pragma unroll
        for (int i = 0; i < 2; ++i) {
            const int r = (wv * 2 + i) * 8 + lrow;
            gload16(Km + ((size_t)bh * 512 + s0 + r) * 64 + gchunk * 8, lds_k + (wv * 2 + i) * 512);
            gload16(Vt + ((size_t)bh * 64 + r) * 512 + s0 + gchunk * 8, lds_v + (wv * 2 + i) * 512);
        }
        __syncthreads();

        // S = Q K^T, scale, causal mask (only bites on the diagonal tile)
        float svv[4][4];
#pragma unroll
        for (int ni = 0; ni < 4; ++ni) {
            f32x4 s = (f32x4){0.f, 0.f, 0.f, 0.f};
#pragma unroll
            for (int ks = 0; ks < 2; ++ks) {
                const int row = ni * 16 + l15;
                const int c   = ks * 4 + l4;
                s16x8 kb = *(const s16x8*)(lds_k + row * 64 + ((c ^ (row & 7)) * 8));
                s = __builtin_amdgcn_mfma_f32_16x16x32_bf16(qa[ks], kb, s, 0, 0, 0);
            }
            const int colg = s0 + ni * 16 + l15;
#pragma unroll
            for (int r = 0; r < 4; ++r)
                svv[ni][r] = (colg > rowg0 + r) ? -1e30f : s[r] * 0.125f;
        }
        // online softmax, per-row stats live in each 16-lane group
#pragma unroll
        for (int r = 0; r < 4; ++r) {
            float mt = fmaxf(fmaxf(svv[0][r], svv[1][r]), fmaxf(svv[2][r], svv[3][r]));
            mt = fmaxf(mt, __shfl_xor(mt, 1, 64));
            mt = fmaxf(mt, __shfl_xor(mt, 2, 64));
            mt = fmaxf(mt, __shfl_xor(mt, 4, 64));
            mt = fmaxf(mt, __shfl_xor(mt, 8, 64));
            const float mn    = fmaxf(m_run[r], mt);
            const float alpha = __expf(m_run[r] - mn);
            m_run[r] = mn;
            float rs = 0.f;
#pragma unroll
            for (int ni = 0; ni < 4; ++ni) {
                const float p = __expf(svv[ni][r] - mn);
                svv[ni][r] = p;
                rs += p;
            }
            rs += __shfl_xor(rs, 1, 64);
            rs += __shfl_xor(rs, 2, 64);
            rs += __shfl_xor(rs, 4, 64);
            rs += __shfl_xor(rs, 8, 64);
            l_run[r] = l_run[r] * alpha + rs;
#pragma unroll
            for (int ni = 0; ni < 4; ++ni) oacc[ni][r] *= alpha;
        }
        // P -> LDS (C/D layout -> A layout transpose through LDS)
#pragma unroll
        for (int ni = 0; ni < 4; ++ni)
#pragma unroll
            for (int r = 0; r < 4; ++r)
                p_lds[wv][(l4 * 4 + r) * 72 + ni * 16 + l15] = f2bf(svv[ni][r]);
        __syncthreads();
        s16x8 pa[2];
        {
            const unsigned short* pp = &p_lds[wv][l15 * 72 + l4 * 8];
            pa[0] = *(const s16x8*)(pp);
            pa[1] = *(const s16x8*)(pp + 32);
        }
#pragma unroll
        for (int ni = 0; ni < 4; ++ni)
#pragma unroll
            for (int ks = 0; ks < 2; ++ks) {
                const int row = ni * 16 + l15;
                const int c   = ks * 4 + l4;
                s16x8 vb = *(const s16x8*)(lds_v + row * 64 + ((c ^ (row & 7)) * 8));
                oacc[ni] = __builtin_amdgcn_mfma_f32_16x16x32_bf16(pa[ks], vb, oacc[ni], 0, 0, 0);
            }
    }
#pragma unroll
    for (int ni = 0; ni < 4; ++ni)
#pragma unroll
        for (int r = 0; r < 4; ++r) {
            const int t = rowg0 + r;
            Om[((size_t)t * BB + b) * DD + h * 64 + ni * 16 + l15] = f2bf(oacc[ni][r] / l_run[r]);
        }
}

// ---------------------------------------------------------------------------
// GRU gate (+ optional fused LayerNorm of the gate output).
//   r=sig(g0) z=sig(g1-bg) h=tanh(g2*r); o=(1-z)*x+z*h
// One block per row: 256 threads x 4 elems = D.
// NOTE: outf may alias xin (same addresses per thread, read-before-write).
// ---------------------------------------------------------------------------
__global__ __launch_bounds__(256, 4)
void gru_gate_ln(const unsigned short* __restrict__ g, const float* xin,
                 const float* __restrict__ bg,
                 const float* __restrict__ lnw, const float* __restrict__ lnb,
                 float* outf,
                 unsigned short* __restrict__ side_bf, int ld_side,
                 unsigned short* __restrict__ lnout_bf) {
    const int row = blockIdx.x;
    const int tid = threadIdx.x;
    const int d   = tid * 4;
    const unsigned short* gp = g + (size_t)row * 3072 + d;
    s16x4 g0 = *(const s16x4*)(gp);
    s16x4 g1 = *(const s16x4*)(gp + 1024);
    s16x4 g2 = *(const s16x4*)(gp + 2048);
    f32x4 xv  = *(const f32x4*)(xin + (size_t)row * DD + d);
    f32x4 bgv = *(const f32x4*)(bg + d);
    f32x4 of;
    s16x4 ob;
#pragma unroll
    for (int j = 0; j < 4; ++j) {
        const float a0 = bf2f((unsigned short)g0[j]);
        const float a1 = bf2f((unsigned short)g1[j]);
        const float a2 = bf2f((unsigned short)g2[j]);
        const float r = 1.f / (1.f + __expf(-a0));
        const float z = 1.f / (1.f + __expf(-(a1 - bgv[j])));
        const float t = a2 * r;
        const float e = __expf(2.f * t);
        const float th = 1.f - 2.f / (e + 1.f);   // tanh, saturates correctly
        const float o = (1.f - z) * xv[j] + z * th;
        of[j] = o;
        ob[j] = (short)f2bf(o);
    }
    *(f32x4*)(outf + (size_t)row * DD + d) = of;
    if (side_bf) *(s16x4*)(side_bf + (size_t)row * ld_side + d) = ob;

    if (lnw) {   // fused LayerNorm over this row's gate output
        float s = of[0] + of[1] + of[2] + of[3];
        float q = of[0]*of[0] + of[1]*of[1] + of[2]*of[2] + of[3]*of[3];
#pragma unroll
        for (int dd = 1; dd < 64; dd <<= 1) {
            s += __shfl_xor(s, dd, 64);
            q += __shfl_xor(q, dd, 64);
        }
        __shared__ float red[8];
        const int lane = tid & 63, wvi = tid >> 6;
        if (lane == 0) { red[wvi] = s; red[4 + wvi] = q; }
        __syncthreads();
        s = red[0] + red[1] + red[2] + red[3];
        q = red[4] + red[5] + red[6] + red[7];
        const float mu   = s * (1.f / 1024.f);
        const float rstd = rsqrtf(q * (1.f / 1024.f) - mu * mu + 1e-5f);
        f32x4 w4 = *(const f32x4*)(lnw + d);
        f32x4 b4 = *(const f32x4*)(lnb + d);
        s16x4 lo;
#pragma unroll
        for (int j = 0; j < 4; ++j) lo[j] = (short)f2bf((of[j] - mu) * rstd * w4[j] + b4[j]);
        *(s16x4*)(lnout_bf + (size_t)row * DD + d) = lo;
    }
}

// ---------------------------------------------------------------------------
// Workspace layout -- TOTAL 176,160,768 bytes (168 MiB). Lifetimes:
//   [0, 50331648)             weights bf16, dict order          (all steps)
//   [50331648, 83886080)      xn_bf (steps 2-3)  -> vT (4-5)
//   [83886080, 184549376)     qkv_bf (3-4); head 32MiB -> aO_bf (5..last c6)
//   chunk region (from 117440512, inside dead qkv tail):
//     [117440512, 134217728)  xc   16 MiB  (xcat1 c5.5-c7; xcat2 c8-c11)
//     [134217728, 142606336)  hbf   8 MiB  (c8-c9)
//     [142606336, 176160768)  gbuf 32 MiB  (g1c c7-c8; ff1c c9-c10; g2c c11-c12)
// d_out (64 MiB): q_bh [0,32M) + k_bh [32M,64M) during steps 4-5;
//                 h1 fp32 (steps c8-c12); final output written by gate2.
// ---------------------------------------------------------------------------
extern "C" void kernel_launch(void* const* d_in, const int* in_sizes, int n_in,
                              void* d_out, int out_size, void* d_ws, size_t ws_size,
                              hipStream_t stream) {
    const float* x     = (const float*)d_in[0];
    const float* w_qkv = (const float*)d_in[1];
    const float* w_out = (const float*)d_in[2];
    const float* b_out = (const float*)d_in[3];
    const float* ln1_w = (const float*)d_in[4];
    const float* ln1_b = (const float*)d_in[5];
    const float* ln2_w = (const float*)d_in[6];
    const float* ln2_b = (const float*)d_in[7];
    const float* w_ff1 = (const float*)d_in[8];
    const float* b_ff1 = (const float*)d_in[9];
    const float* w_ff2 = (const float*)d_in[10];
    const float* b_ff2 = (const float*)d_in[11];
    const float* g1_w  = (const float*)d_in[12];
    const float* g1_bg = (const float*)d_in[13];
    const float* g2_w  = (const float*)d_in[14];
    const float* g2_bg = (const float*)d_in[15];

    float* out = (float*)d_out;

    if (ws_size < 176160768ULL) {
        // ws too small for this plan: write an unmistakable marker so the
        // bench error (~1e6) distinguishes this from a numerics bug.
        fill_f32<<<16384, 256, 0, stream>>>(out, 1.0e6f);
        return;
    }

    char* ws = (char*)d_ws;
    unsigned short* wall  = (unsigned short*)(ws + 0);
    unsigned short* wq_b  = (unsigned short*)(ws + 0);
    unsigned short* wo_b  = (unsigned short*)(ws + 6291456);
    unsigned short* wf1_b = (unsigned short*)(ws + 8388608);
    unsigned short* wf2_b = (unsigned short*)(ws + 16777216);
    unsigned short* wg1_b = (unsigned short*)(ws + 25165824);
    unsigned short* wg2_b = (unsigned short*)(ws + 37748736);
    unsigned short* xn_bf  = (unsigned short*)(ws + 50331648);
    unsigned short* vT_bh  = xn_bf;                             // after xn dead
    unsigned short* qkv_bf = (unsigned short*)(ws + 83886080);
    unsigned short* aO_bf  = qkv_bf;                            // after qkv dead
    unsigned short* xc   = (unsigned short*)(ws + 117440512);
    unsigned short* hbf  = (unsigned short*)(ws + 134217728);
    unsigned short* gbuf = (unsigned short*)(ws + 142606336);

    unsigned short* q_bh = (unsigned short*)d_out;              // steps 4-5
    unsigned short* k_bh = q_bh + 16777216;
    float*          h1   = out;                                 // steps c8-c12

    // 1. all weights -> bf16 (one launch; dsts contiguous in ws)
    cvt_weights<<<24576, 256, 0, stream>>>(w_qkv, w_out, w_ff1, w_ff2, g1_w, g2_w, wall);

    // 2. LN1
    ln_fwd<<<NROW, 256, 0, stream>>>(x, ln1_w, ln1_b, xn_bf, nullptr, 0);

    // 3. qkv = ln1 @ w_qkv.T
    gemm_bf16<<<dim3(24, 128), 256, 0, stream>>>(xn_bf, wq_b, qkv_bf, nullptr,
                                                 NROW, 3072, 1024, 3072, 0);
    // 4. repack q/k (-> d_out) and vT (-> ws)
    repack_qkv<<<dim3(8, 512), 256, 0, stream>>>(qkv_bf, q_bh, k_bh, vT_bh);

    // 5. attention -> aO_bf (overlays dead qkv head)
    attn_fwd<<<dim3(8, 512), 256, 0, stream>>>(q_bh, k_bh, vT_bh, aO_bf);

    // 6-12. row-chunked tail: 4 chunks x 4096 rows
    const int RCH = 4096;
    for (int c = 0; c < 4; ++c) {
        const int r0 = c * RCH;
        // c5.5: x chunk -> bf16 into xc half 1
        cvt_rows<<<RCH, 256, 0, stream>>>(x + (size_t)r0 * DD, xc, 2048);
        // c6: out-proj (+b_out) -> xc half 2
        gemm_bf16<<<dim3(8, RCH / 128), 256, 0, stream>>>(
            aO_bf + (size_t)r0 * 1024, wo_b, xc + 1024, b_out, RCH, 1024, 1024, 2048, 0);
        // c7: g1 = [x, attn_proj] @ g1_w.T
        gemm_bf16<<<dim3(24, RCH / 128), 256, 0, stream>>>(
            xc, wg1_b, gbuf, nullptr, RCH, 3072, 2048, 3072, 0);
        // c8: gate1 -> h1 (d_out) + bf16(h1) -> xc half 1 + fused LN2 -> hbf
        gru_gate_ln<<<RCH, 256, 0, stream>>>(gbuf, x + (size_t)r0 * DD, g1_bg,
                                             ln2_w, ln2_b, h1 + (size_t)r0 * DD,
                                             xc, 2048, hbf);
        // c9: ff1 (+bias, relu)
        gemm_bf16<<<dim3(32, RCH / 128), 256, 0, stream>>>(
            hbf, wf1_b, gbuf, b_ff1, RCH, 4096, 1024, 4096, 1);
        // c10: ff2 (+bias) -> xc half 2
        gemm_bf16<<<dim3(8, RCH / 128), 256, 0, stream>>>(
            gbuf, wf2_b, xc + 1024, b_ff2, RCH, 1024, 4096, 2048, 0);
        // c11: g2 = [h1, ff] @ g2_w.T
        gemm_bf16<<<dim3(24, RCH / 128), 256, 0, stream>>>(
            xc, wg2_b, gbuf, nullptr, RCH, 3072, 2048, 3072, 0);
        // c12: gate2 (reads h1 from d_out, writes final output in place)
        gru_gate_ln<<<RCH, 256, 0, stream>>>(gbuf, h1 + (size_t)r0 * DD, g2_bg,
                                             nullptr, nullptr, h1 + (size_t)r0 * DD,
                                             nullptr, 0, nullptr);
    }
}